// Round 1
// 65.392 us; speedup vs baseline: 1.1025x; 1.1025x over previous
//
#include <hip/hip_runtime.h>

#define NN 512
#define DD 128
#define MARGIN_F 0.3f

// Kernel 0 (NEW this round): transpose x [512][128] -> xT [128][512] in ws.
// x is 256 KB (L2-resident); this runs once per graph replay (~1-2 us).
// Motivation: k1's old per-thread-row loads made every wave instruction
// touch 64 distinct cache lines (lane stride 512 B) -> L1 line-rate bound
// (~30 us). Reading xT[c*512 + tid] is lane-consecutive -> coalesced.
__global__ __launch_bounds__(256) void transpose_kernel(
    const float* __restrict__ x,
    float* __restrict__ xT) {

    __shared__ float tile[32][DD + 1];   // +1 pad: conflict-free column reads
    const int r0 = blockIdx.x * 32;
    const int tid = threadIdx.x;

#pragma unroll
    for (int it = 0; it < 16; ++it) {
        int idx = it * 256 + tid;        // 0..4095 over 32 rows x 128 cols
        int r = idx >> 7;
        int c = idx & 127;
        tile[r][c] = x[(r0 + r) * DD + c];   // coalesced global read
    }
    __syncthreads();
#pragma unroll
    for (int it = 0; it < 16; ++it) {
        int idx = it * 256 + tid;
        int c = idx >> 5;                // 0..127
        int j = idx & 31;                // 0..31
        // write: consecutive tid -> consecutive xT addresses (32-elem runs)
        // LDS read tile[j][c]: bank (j*129+c)%32 = (j+c)%32 -> conflict-free
        xT[c * NN + r0 + j] = tile[j][c];
    }
}

// Kernel 1: block i computes distance row d[i][*] from xT (coalesced),
// compacts positives into an LDS list, reduces relu(d_ij + margin - d_ik)
// over negatives k, writes one (sum,cnt) partial per block.
// Triplet phase unchanged from the 71.5us winner.
// NOTE (R4 lesson): do NOT fuse the final reduce via device-scope flag spin —
// polling coherent atomics costs ~9 us vs ~2 us for a second graph node.
__global__ __launch_bounds__(512) void triplet_partial_kernel(
    const float* __restrict__ x,
    const float* __restrict__ xT,
    const int* __restrict__ labels,
    float* __restrict__ psum,
    unsigned int* __restrict__ pcnt) {

    const int i = blockIdx.x;
    const int tid = threadIdx.x;   // one j (and one k) per thread

    __shared__ __align__(16) float xi[DD];
    __shared__ float ds[NN];
    __shared__ int ls[NN];
    __shared__ float tvals[NN];    // d_ij + margin for each positive j
    __shared__ int npos;
    __shared__ float wsum[8];
    __shared__ unsigned int wcnt[8];

    if (tid < DD) xi[tid] = x[i * DD + tid];
    if (tid == 0) npos = 0;
    ls[tid] = labels[tid];
    __syncthreads();

    const int li = ls[i];

    // Distance row + positive compaction (j == tid).
    // xT reads: lane-consecutive (stride 4 B) -> fully coalesced, L2-hit.
    // xi reads: LDS b128 broadcast (same addr all lanes) -> conflict-free.
    {
        const float* xTc = xT + tid;
        float acc = 0.0f;
#pragma unroll 4
        for (int c4 = 0; c4 < DD / 4; ++c4) {
            float4 u = ((const float4*)xi)[c4];
            float v0 = xTc[(c4 * 4 + 0) * NN];
            float v1 = xTc[(c4 * 4 + 1) * NN];
            float v2 = xTc[(c4 * 4 + 2) * NN];
            float v3 = xTc[(c4 * 4 + 3) * NN];
            float a0 = u.x - v0;
            float a1 = u.y - v1;
            float a2 = u.z - v2;
            float a3 = u.w - v3;
            acc = fmaf(a0, a0, acc);
            acc = fmaf(a1, a1, acc);
            acc = fmaf(a2, a2, acc);
            acc = fmaf(a3, a3, acc);
        }
        float dj = sqrtf(acc);
        ds[tid] = dj;
        if (ls[tid] == li && tid != i) {
            int p = atomicAdd(&npos, 1);         // LDS atomic, ~10 per block
            tvals[p] = dj + MARGIN_F;
        }
    }
    __syncthreads();

    // Triplet reduction: thread tid owns k == tid.
    const int np = npos;
    float lsum = 0.0f;
    unsigned int lcnt = 0u;
    if (ls[tid] != li) {                         // negative k (excludes k==i)
        const float dk = ds[tid];
        for (int p = 0; p < np; ++p) {
            float v = tvals[p] - dk;
            lsum += fmaxf(v, 0.0f);
            lcnt += (v > 1e-16f) ? 1u : 0u;
        }
    }

    // Wave (64) shuffle reduction, then cross-wave via LDS (8 waves).
    for (int off = 32; off > 0; off >>= 1) {
        lsum += __shfl_down(lsum, off);
        lcnt += __shfl_down(lcnt, off);
    }
    const int wave = tid >> 6;
    const int lane = tid & 63;
    if (lane == 0) { wsum[wave] = lsum; wcnt[wave] = lcnt; }
    __syncthreads();

    if (tid == 0) {
        float bs = 0.0f;
        unsigned int bc = 0u;
#pragma unroll
        for (int w = 0; w < 8; ++w) { bs += wsum[w]; bc += wcnt[w]; }
        psum[i] = bs;                            // plain stores, slot per block
        pcnt[i] = bc;
    }
}

// Kernel 2: reduce 512 partials -> scalar. ONE wave (64 threads): no LDS,
// no __syncthreads, serial 8-partial accumulate + shuffle tree. Kernel
// boundary gives cross-XCD visibility of kernel-1 stores (R3 verified).
__global__ __launch_bounds__(64) void reduce_kernel(
    const float* __restrict__ psum,
    const unsigned int* __restrict__ pcnt,
    float* __restrict__ out) {

    const int tid = threadIdx.x;
    float lsum = 0.0f;
    unsigned int lcnt = 0u;
#pragma unroll
    for (int w = 0; w < NN / 64; ++w) {
        lsum += psum[w * 64 + tid];
        lcnt += pcnt[w * 64 + tid];
    }
    for (int off = 32; off > 0; off >>= 1) {
        lsum += __shfl_down(lsum, off);
        lcnt += __shfl_down(lcnt, off);
    }
    if (tid == 0) out[0] = lsum / ((float)lcnt + 1e-16f);
}

extern "C" void kernel_launch(void* const* d_in, const int* in_sizes, int n_in,
                              void* d_out, int out_size, void* d_ws, size_t ws_size,
                              hipStream_t stream) {
    const float* x = (const float*)d_in[0];     // [512,128] fp32
    const int* labels = (const int*)d_in[1];    // [512] int32
    float* out = (float*)d_out;                 // scalar fp32

    float* psum = (float*)d_ws;                               // 512 floats
    unsigned int* pcnt = (unsigned int*)((char*)d_ws + 2048); // 512 uints
    float* xT = (float*)((char*)d_ws + 4096);                 // [128][512] = 256 KB

    transpose_kernel<<<NN / 32, 256, 0, stream>>>(x, xT);
    triplet_partial_kernel<<<NN, 512, 0, stream>>>(x, xT, labels, psum, pcnt);
    reduce_kernel<<<1, 64, 0, stream>>>(psum, pcnt, out);
}

// Round 2
// 63.118 us; speedup vs baseline: 1.1422x; 1.0360x over previous
//
#include <hip/hip_runtime.h>

#define NN 512
#define DD 128
#define MARGIN_F 0.3f
#define TS 32          // distance-matrix tile (32x32), 16x16 tile grid
#define PADW 132       // 128 + 4 pad floats; 132*4=528 B row stride, 16B-aligned

// Kernel A (NEW this round): distance matrix via the Gram trick, tiled.
// d2[i][j] = n_i + n_j - 2*x_i.x_j  (the reference's own formula, fp32).
// Replaces the old per-row-block recompute (every block streamed all 256 KB
// of x -> 128 MB L2 traffic, L1 set-thrash on the 2048-B column stride).
// Here: 256 blocks, each stages two 32x128 tiles in LDS (full reuse),
// L2 traffic ~16 MB total. Row norms computed in-register during staging
// via half-wave shuffle reductions (each half-wave stages exactly one row
// per iteration). Output D [512][512] fp32 = 1 MB, L2-resident.
__global__ __launch_bounds__(256) void dist_tile_kernel(
    const float* __restrict__ x,
    float* __restrict__ D) {

    const int bi = blockIdx.x >> 4;    // tile row
    const int bj = blockIdx.x & 15;    // tile col
    const int t  = threadIdx.x;

    __shared__ __align__(16) float As[TS][PADW];
    __shared__ __align__(16) float Bs[TS][PADW];
    __shared__ float nA[TS];
    __shared__ float nB[TS];

    const float4* xa = (const float4*)(x + bi * TS * DD);
    const float4* xb = (const float4*)(x + bj * TS * DD);

    // Stage 32x128 A-tile and B-tile (coalesced float4) + in-register norms.
    // Per it, each half-wave (32 lanes) covers exactly one row (32 float4/row).
#pragma unroll
    for (int it = 0; it < 4; ++it) {
        int f = it * 256 + t;          // 0..1023 float4 index
        int r = f >> 5;
        int c4 = f & 31;
        float4 va = xa[f];
        float4 vb = xb[f];
        *(float4*)&As[r][c4 * 4] = va;
        *(float4*)&Bs[r][c4 * 4] = vb;
        float sa = va.x * va.x + va.y * va.y + va.z * va.z + va.w * va.w;
        float sb = vb.x * vb.x + vb.y * vb.y + vb.z * vb.z + vb.w * vb.w;
#pragma unroll
        for (int m = 16; m >= 1; m >>= 1) {
            sa += __shfl_xor(sa, m, 32);   // width 32: stay inside half-wave
            sb += __shfl_xor(sb, m, 32);
        }
        if ((t & 31) == 0) { nA[r] = sa; nB[r] = sb; }
    }
    __syncthreads();

    // 2x2 micro-tile per thread: rows {2ty,2ty+1}, cols {2tx,2tx+1}.
    // A-reads broadcast across tx (free); B-reads 4-way bank conflict (PADW=132
    // -> base banks {0,8,16,24}) — acceptable, b128 floor dominates.
    const int ty = t >> 4;
    const int tx = t & 15;
    float acc00 = 0.f, acc01 = 0.f, acc10 = 0.f, acc11 = 0.f;
#pragma unroll
    for (int k4 = 0; k4 < 32; ++k4) {
        float4 a0 = *(const float4*)&As[2 * ty][k4 * 4];
        float4 a1 = *(const float4*)&As[2 * ty + 1][k4 * 4];
        float4 b0 = *(const float4*)&Bs[2 * tx][k4 * 4];
        float4 b1 = *(const float4*)&Bs[2 * tx + 1][k4 * 4];
        acc00 = fmaf(a0.x, b0.x, acc00); acc00 = fmaf(a0.y, b0.y, acc00);
        acc00 = fmaf(a0.z, b0.z, acc00); acc00 = fmaf(a0.w, b0.w, acc00);
        acc01 = fmaf(a0.x, b1.x, acc01); acc01 = fmaf(a0.y, b1.y, acc01);
        acc01 = fmaf(a0.z, b1.z, acc01); acc01 = fmaf(a0.w, b1.w, acc01);
        acc10 = fmaf(a1.x, b0.x, acc10); acc10 = fmaf(a1.y, b0.y, acc10);
        acc10 = fmaf(a1.z, b0.z, acc10); acc10 = fmaf(a1.w, b0.w, acc10);
        acc11 = fmaf(a1.x, b1.x, acc11); acc11 = fmaf(a1.y, b1.y, acc11);
        acc11 = fmaf(a1.z, b1.z, acc11); acc11 = fmaf(a1.w, b1.w, acc11);
    }

    // Epilogue: d = sqrt(max(n_i + n_j - 2*g, 0)); matches reference's
    // safe-sqrt (sq<=0 -> 0). float2 stores, cols contiguous.
    const float n0 = nA[2 * ty], n1 = nA[2 * ty + 1];
    const float m0 = nB[2 * tx], m1 = nB[2 * tx + 1];
    float2 r0, r1;
    r0.x = sqrtf(fmaxf(n0 + m0 - 2.f * acc00, 0.f));
    r0.y = sqrtf(fmaxf(n0 + m1 - 2.f * acc01, 0.f));
    r1.x = sqrtf(fmaxf(n1 + m0 - 2.f * acc10, 0.f));
    r1.y = sqrtf(fmaxf(n1 + m1 - 2.f * acc11, 0.f));
    const int gr = bi * TS + 2 * ty;
    const int gc = bj * TS + 2 * tx;
    *(float2*)&D[gr * NN + gc] = r0;
    *(float2*)&D[(gr + 1) * NN + gc] = r1;
}

// Kernel B: triplet phase. Block i reads its precomputed D-row (2 KB,
// coalesced, L2-hit), compacts positives into an LDS list, reduces
// relu(d_ij + margin - d_ik) over negatives k, writes one (sum,cnt)
// partial per block. Unconditional stores -> no ws init.
// NOTE (R4 lesson): do NOT fuse the final reduce via device-scope flag spin —
// polling coherent atomics costs ~9 us vs ~2 us for a second graph node.
__global__ __launch_bounds__(512) void triplet_partial_kernel(
    const float* __restrict__ D,
    const int* __restrict__ labels,
    float* __restrict__ psum,
    unsigned int* __restrict__ pcnt) {

    const int i = blockIdx.x;
    const int tid = threadIdx.x;   // one j (and one k) per thread

    __shared__ int ls[NN];
    __shared__ float tvals[NN];    // d_ij + margin for each positive j
    __shared__ int npos;
    __shared__ float wsum[8];
    __shared__ unsigned int wcnt[8];

    if (tid == 0) npos = 0;
    const float dj = D[i * NN + tid];   // d_ij; also d_ik for k==tid
    ls[tid] = labels[tid];
    __syncthreads();

    const int li = ls[i];
    if (ls[tid] == li && tid != i) {
        int p = atomicAdd(&npos, 1);    // LDS atomic, ~10 per block
        tvals[p] = dj + MARGIN_F;
    }
    __syncthreads();

    // Triplet reduction: thread tid owns k == tid (dk == dj).
    const int np = npos;
    float lsum = 0.0f;
    unsigned int lcnt = 0u;
    if (ls[tid] != li) {                // negative k (excludes k==i)
        for (int p = 0; p < np; ++p) {
            float v = tvals[p] - dj;    // tvals broadcast read
            lsum += fmaxf(v, 0.0f);
            lcnt += (v > 1e-16f) ? 1u : 0u;
        }
    }

    // Wave (64) shuffle reduction, then cross-wave via LDS (8 waves).
    for (int off = 32; off > 0; off >>= 1) {
        lsum += __shfl_down(lsum, off);
        lcnt += __shfl_down(lcnt, off);
    }
    const int wave = tid >> 6;
    const int lane = tid & 63;
    if (lane == 0) { wsum[wave] = lsum; wcnt[wave] = lcnt; }
    __syncthreads();

    if (tid == 0) {
        float bs = 0.0f;
        unsigned int bc = 0u;
#pragma unroll
        for (int w = 0; w < 8; ++w) { bs += wsum[w]; bc += wcnt[w]; }
        psum[i] = bs;                   // plain stores, slot per block
        pcnt[i] = bc;
    }
}

// Kernel C: reduce 512 partials -> scalar. ONE wave (64 threads): no LDS,
// no __syncthreads, serial 8-partial accumulate + shuffle tree. Kernel
// boundary gives cross-XCD visibility of kernel-B stores (R3 verified).
__global__ __launch_bounds__(64) void reduce_kernel(
    const float* __restrict__ psum,
    const unsigned int* __restrict__ pcnt,
    float* __restrict__ out) {

    const int tid = threadIdx.x;
    float lsum = 0.0f;
    unsigned int lcnt = 0u;
#pragma unroll
    for (int w = 0; w < NN / 64; ++w) {
        lsum += psum[w * 64 + tid];
        lcnt += pcnt[w * 64 + tid];
    }
    for (int off = 32; off > 0; off >>= 1) {
        lsum += __shfl_down(lsum, off);
        lcnt += __shfl_down(lcnt, off);
    }
    if (tid == 0) out[0] = lsum / ((float)lcnt + 1e-16f);
}

extern "C" void kernel_launch(void* const* d_in, const int* in_sizes, int n_in,
                              void* d_out, int out_size, void* d_ws, size_t ws_size,
                              hipStream_t stream) {
    const float* x = (const float*)d_in[0];     // [512,128] fp32
    const int* labels = (const int*)d_in[1];    // [512] int32
    float* out = (float*)d_out;                 // scalar fp32

    float* psum = (float*)d_ws;                               // 512 floats
    unsigned int* pcnt = (unsigned int*)((char*)d_ws + 2048); // 512 uints
    float* Dm = (float*)((char*)d_ws + 4096);                 // [512][512] = 1 MB

    dist_tile_kernel<<<256, 256, 0, stream>>>(x, Dm);
    triplet_partial_kernel<<<NN, 512, 0, stream>>>(Dm, labels, psum, pcnt);
    reduce_kernel<<<1, 64, 0, stream>>>(psum, pcnt, out);
}